// Round 2
// baseline (562.015 us; speedup 1.0000x reference)
//
#include <hip/hip_runtime.h>
#include <hip/hip_bf16.h>
#include <math.h>

// ---------------- types ----------------
typedef __attribute__((ext_vector_type(4))) float   f32x4;
typedef __attribute__((ext_vector_type(8))) short   short8;
typedef __attribute__((ext_vector_type(8))) __bf16  bf16x8;

union SB8 { short8 s; bf16x8 b; };

__device__ __forceinline__ short f2bf(float f) {
  union { float f; unsigned u; } v; v.f = f;
  unsigned r = v.u + 0x7fffu + ((v.u >> 16) & 1u);   // RNE
  return (short)(r >> 16);
}

__device__ __forceinline__ short8 cvt8(f32x4 a, f32x4 b) {
  short8 r;
  r[0] = f2bf(a[0]); r[1] = f2bf(a[1]); r[2] = f2bf(a[2]); r[3] = f2bf(a[3]);
  r[4] = f2bf(b[0]); r[5] = f2bf(b[1]); r[6] = f2bf(b[2]); r[7] = f2bf(b[3]);
  return r;
}

// Problem constants
#define TT   2048
#define DD   1024
#define HH   704
#define HSS  1408
#define EE   16
#define KK_ACT 4
#define CAP  2048          // per-expert token capacity

// ---------------- gate ----------------
// One block per token. fp64 logits (tie-flip safety), serial routing on thread 0.
__global__ __launch_bounds__(256)
void gate_kernel(const float* __restrict__ x, const float* __restrict__ gw,
                 const float* __restrict__ gb,
                 int* __restrict__ counts, int* __restrict__ tok,
                 float* __restrict__ wgt)
{
  const int t = blockIdx.x;
  const int tid = threadIdx.x;
  const float* xp = x + (size_t)t * DD;

  double acc[EE];
  #pragma unroll
  for (int e = 0; e < EE; e++) acc[e] = 0.0;

  for (int d = tid; d < DD; d += 256) {
    double xv = (double)xp[d];
    #pragma unroll
    for (int e = 0; e < EE; e++) acc[e] += xv * (double)gw[e * DD + d];
  }

  __shared__ double red[256 * EE];
  __shared__ double red2[16 * EE];
  __shared__ double logit[EE];
  #pragma unroll
  for (int e = 0; e < EE; e++) red[tid * EE + e] = acc[e];
  __syncthreads();
  {
    int e = tid & 15, i0 = tid >> 4;        // 256 threads -> 16 partials per expert
    double s = 0.0;
    for (int i = i0; i < 256; i += 16) s += red[i * EE + e];
    red2[i0 * EE + e] = s;
  }
  __syncthreads();
  if (tid < EE) {
    double s = 0.0;
    for (int i = 0; i < 16; i++) s += red2[i * EE + tid];
    logit[tid] = s;
  }
  __syncthreads();

  if (tid == 0) {
    double sc[EE], r[EE];
    #pragma unroll
    for (int e = 0; e < EE; e++) {
      double l = logit[e];
      double sg = 1.0 / (1.0 + exp(-l));
      sc[e] = sg;
      r[e] = sg + (double)gb[e];
    }
    // group scores = sum of top-2 within each group of 4
    double gs[4];
    #pragma unroll
    for (int g = 0; g < 4; g++) {
      double m1 = -1e300, m2 = -1e300;
      for (int j = 0; j < 4; j++) {
        double v = r[g * 4 + j];
        if (v > m1) { m2 = m1; m1 = v; }
        else if (v > m2) { m2 = v; }
      }
      gs[g] = m1 + m2;
    }
    // top-2 groups
    int g1 = 0, g2 = -1; double b1 = -1e300, b2 = -1e300;
    for (int g = 0; g < 4; g++) {
      if (gs[g] > b1) { b2 = b1; g2 = g1; b1 = gs[g]; g1 = g; }
      else if (gs[g] > b2) { b2 = gs[g]; g2 = g; }
    }
    bool keep[EE];
    #pragma unroll
    for (int e = 0; e < EE; e++) { int g = e >> 2; keep[e] = (g == g1) || (g == g2); }
    // top-4 experts among kept (tie -> lowest index), weights from un-biased scores
    int idx[KK_ACT]; double wv[KK_ACT]; double wsum = 0.0;
    bool used[EE] = {false};
    for (int k = 0; k < KK_ACT; k++) {
      double best = -1e300; int bi = 0;
      for (int e = 0; e < EE; e++)
        if (keep[e] && !used[e] && r[e] > best) { best = r[e]; bi = e; }
      used[bi] = true; idx[k] = bi; wv[k] = sc[bi]; wsum += sc[bi];
    }
    double div = wsum < 1e-9 ? 1e-9 : wsum;
    for (int k = 0; k < KK_ACT; k++) {
      float w = (float)(wv[k] / div * 2.5446);
      int slot = atomicAdd(&counts[idx[k]], 1);
      tok[idx[k] * CAP + slot] = t;
      wgt[idx[k] * CAP + slot] = w;
    }
  }
}

// ---------------- GEMM1 + SwiGLU ----------------
// act[m][n] = silu(X Wg^T) * (X Wu^T).  Block tile 64m x 64n, K=1024.
// 4 waves: wave w -> 4 m-tiles (16x16) at n-tile w.
// LDS tiles stored MFMA-swizzled: chunk(r,kc) at index (r>>4)*64 + kc*16 + (r&15);
// lane L of m-tile mt reads chunk mt*64+L  -> conflict-free ds_read_b128.
template<bool GATHER>
__global__ __launch_bounds__(256)
void gemm1_kernel(const float* __restrict__ x, const float* __restrict__ W1g,
                  const float* __restrict__ W3g, short* __restrict__ act,
                  const int* __restrict__ counts, const int* __restrict__ tok,
                  const int N, const int T)
{
  const int K = DD;
  const int e = GATHER ? blockIdx.z : 0;
  const int cnt = GATHER ? counts[e] : T;
  const int Mt = blockIdx.y, Nt = blockIdx.x;
  if (Mt * 64 >= cnt) return;

  const float* W1 = W1g + (size_t)e * N * K;
  const float* W3 = W3g + (size_t)e * N * K;
  short* actp = act + (GATHER ? (size_t)e * CAP * N : (size_t)0);

  __shared__ __align__(16) short lX[64 * 32];
  __shared__ __align__(16) short lW1[64 * 32];
  __shared__ __align__(16) short lW3[64 * 32];

  const int tid = threadIdx.x;
  const int lane = tid & 63;
  const int wv = tid >> 6;
  const int sr = tid >> 2;        // staging row 0..63
  const int skc = tid & 3;        // staging k-chunk 0..3

  bool xvalid = true;
  int xrow = Mt * 64 + sr;
  if (GATHER) {
    xvalid = (xrow < cnt);
    xrow = xvalid ? tok[e * CAP + xrow] : 0;
  }
  const float* xp = x + (size_t)xrow * K + skc * 8;
  const float* w1p = W1 + (size_t)(Nt * 64 + sr) * K + skc * 8;
  const float* w3p = W3 + (size_t)(Nt * 64 + sr) * K + skc * 8;

  const int sci = ((sr >> 4) << 6) + (skc << 4) + (sr & 15);
  short* dX = lX + sci * 8;
  short* dW1 = lW1 + sci * 8;
  short* dW3 = lW3 + sci * 8;

  f32x4 zero4; zero4[0] = zero4[1] = zero4[2] = zero4[3] = 0.f;
  f32x4 acc1[4], acc3[4];
  #pragma unroll
  for (int i = 0; i < 4; i++) { acc1[i] = zero4; acc3[i] = zero4; }

  for (int kk = 0; kk < K; kk += 32) {
    if (kk) __syncthreads();
    short8 vx, v1, v3;
    if (xvalid) {
      f32x4 a = *(const f32x4*)(xp + kk);
      f32x4 b = *(const f32x4*)(xp + kk + 4);
      vx = cvt8(a, b);
    } else {
      short z = 0;
      vx[0] = z; vx[1] = z; vx[2] = z; vx[3] = z;
      vx[4] = z; vx[5] = z; vx[6] = z; vx[7] = z;
    }
    { f32x4 a = *(const f32x4*)(w1p + kk); f32x4 b = *(const f32x4*)(w1p + kk + 4); v1 = cvt8(a, b); }
    { f32x4 a = *(const f32x4*)(w3p + kk); f32x4 b = *(const f32x4*)(w3p + kk + 4); v3 = cvt8(a, b); }
    *(short8*)dX = vx;
    *(short8*)dW1 = v1;
    *(short8*)dW3 = v3;
    __syncthreads();

    SB8 bf1, bf3;
    bf1.s = ((const short8*)lW1)[wv * 64 + lane];
    bf3.s = ((const short8*)lW3)[wv * 64 + lane];
    #pragma unroll
    for (int mt = 0; mt < 4; mt++) {
      SB8 af;
      af.s = ((const short8*)lX)[mt * 64 + lane];
      acc1[mt] = __builtin_amdgcn_mfma_f32_16x16x32_bf16(af.b, bf1.b, acc1[mt], 0, 0, 0);
      acc3[mt] = __builtin_amdgcn_mfma_f32_16x16x32_bf16(af.b, bf3.b, acc3[mt], 0, 0, 0);
    }
  }

  // epilogue: C/D layout col=lane&15, row=quad*4+reg
  const int quad = lane >> 4;
  const int col = Nt * 64 + wv * 16 + (lane & 15);
  #pragma unroll
  for (int mt = 0; mt < 4; mt++) {
    #pragma unroll
    for (int rg = 0; rg < 4; rg++) {
      int r = Mt * 64 + mt * 16 + quad * 4 + rg;
      if (r < cnt) {
        float g = acc1[mt][rg], u = acc3[mt][rg];
        float a = g / (1.f + __expf(-g)) * u;   // silu(g)*u
        actp[(size_t)r * N + col] = f2bf(a);
      }
    }
  }
}

// ---------------- GEMM2 (down proj) ----------------
// out = act @ W^T.  Block tile 64m x 128n; wave w -> 4 m-tiles x 2 n-tiles.
// GATHER: atomicAdd(y[tok], gatew * v).  !GATHER: plain store (covers all of y).
template<bool GATHER>
__global__ __launch_bounds__(256)
void gemm2_kernel(const short* __restrict__ A, const float* __restrict__ Wg,
                  float* __restrict__ y, const int* __restrict__ counts,
                  const int* __restrict__ tok, const float* __restrict__ wgt,
                  const int Kd, const int T)
{
  const int e = GATHER ? blockIdx.z : 0;
  const int cnt = GATHER ? counts[e] : T;
  const int Mt = blockIdx.y, Nt = blockIdx.x;
  if (Mt * 64 >= cnt) return;

  const short* Ap = A + (GATHER ? (size_t)e * CAP * Kd : (size_t)0);
  const float* Wp = Wg + (size_t)e * DD * Kd;

  __shared__ __align__(16) short lA[64 * 32];
  __shared__ __align__(16) short lW[128 * 32];

  const int tid = threadIdx.x;
  const int lane = tid & 63;
  const int wv = tid >> 6;

  // A staging: row 0..63, chunk 0..3
  const int ra = tid >> 2, ca = tid & 3;
  const bool avalid = (Mt * 64 + ra) < cnt;
  const short* ap = Ap + (size_t)(Mt * 64 + ra) * Kd + ca * 8;
  const int sciA = ((ra >> 4) << 6) + (ca << 4) + (ra & 15);
  // W staging: row 0..127, two chunks per thread
  const int rw = tid >> 1, cw0 = (tid & 1) * 2;
  const float* wp = Wp + (size_t)(Nt * 128 + rw) * Kd + cw0 * 8;
  const int sciW0 = ((rw >> 4) << 6) + (cw0 << 4) + (rw & 15);
  const int sciW1 = ((rw >> 4) << 6) + ((cw0 + 1) << 4) + (rw & 15);

  f32x4 zero4; zero4[0] = zero4[1] = zero4[2] = zero4[3] = 0.f;
  f32x4 acc[4][2];
  #pragma unroll
  for (int i = 0; i < 4; i++) { acc[i][0] = zero4; acc[i][1] = zero4; }

  for (int kk = 0; kk < Kd; kk += 32) {
    if (kk) __syncthreads();
    short8 va;
    if (avalid) {
      va = *(const short8*)(ap + kk);
    } else {
      short z = 0;
      va[0] = z; va[1] = z; va[2] = z; va[3] = z;
      va[4] = z; va[5] = z; va[6] = z; va[7] = z;
    }
    f32x4 w0a = *(const f32x4*)(wp + kk);
    f32x4 w0b = *(const f32x4*)(wp + kk + 4);
    f32x4 w1a = *(const f32x4*)(wp + kk + 8);
    f32x4 w1b = *(const f32x4*)(wp + kk + 12);
    *(short8*)(lA + sciA * 8) = va;
    *(short8*)(lW + sciW0 * 8) = cvt8(w0a, w0b);
    *(short8*)(lW + sciW1 * 8) = cvt8(w1a, w1b);
    __syncthreads();

    SB8 b0, b1;
    b0.s = ((const short8*)lW)[(wv * 2 + 0) * 64 + lane];
    b1.s = ((const short8*)lW)[(wv * 2 + 1) * 64 + lane];
    #pragma unroll
    for (int mt = 0; mt < 4; mt++) {
      SB8 af;
      af.s = ((const short8*)lA)[mt * 64 + lane];
      acc[mt][0] = __builtin_amdgcn_mfma_f32_16x16x32_bf16(af.b, b0.b, acc[mt][0], 0, 0, 0);
      acc[mt][1] = __builtin_amdgcn_mfma_f32_16x16x32_bf16(af.b, b1.b, acc[mt][1], 0, 0, 0);
    }
  }

  const int quad = lane >> 4;
  const int colb = Nt * 128 + wv * 32 + (lane & 15);
  #pragma unroll
  for (int mt = 0; mt < 4; mt++) {
    #pragma unroll
    for (int j = 0; j < 2; j++) {
      #pragma unroll
      for (int rg = 0; rg < 4; rg++) {
        int slot = Mt * 64 + mt * 16 + quad * 4 + rg;
        int col = colb + j * 16;
        float v = acc[mt][j][rg];
        if (GATHER) {
          if (slot < cnt) {
            int t = tok[e * CAP + slot];
            float w = wgt[e * CAP + slot];
            atomicAdd(&y[(size_t)t * DD + col], w * v);
          }
        } else {
          y[(size_t)slot * DD + col] = v;
        }
      }
    }
  }
}

// ---------------- launch ----------------
extern "C" void kernel_launch(void* const* d_in, const int* in_sizes, int n_in,
                              void* d_out, int out_size, void* d_ws, size_t ws_size,
                              hipStream_t stream) {
  const float* x      = (const float*)d_in[0];
  const float* gate_w = (const float*)d_in[1];
  const float* gate_b = (const float*)d_in[2];
  const float* w1     = (const float*)d_in[3];
  const float* w3     = (const float*)d_in[4];
  const float* w2     = (const float*)d_in[5];
  const float* ws1    = (const float*)d_in[6];
  const float* ws3    = (const float*)d_in[7];
  const float* ws2    = (const float*)d_in[8];
  float* y = (float*)d_out;

  char* ws = (char*)d_ws;
  // workspace layout (total ~52.2 MB)
  int*   counts = (int*)ws;                                   // 16 ints (256 B pad)
  int*   tok    = (int*)(ws + 256);                           // 16*2048 ints
  float* wgt    = (float*)(ws + 256 + (size_t)EE * CAP * 4);  // 16*2048 floats
  short* act    = (short*)(ws + 256 + (size_t)EE * CAP * 8);  // routed act bf16 [E][CAP][H]
  short* acts   = act + (size_t)EE * CAP * HH;                // shared act bf16 [T][HS]

  (void)hipMemsetAsync(counts, 0, 256, stream);

  gate_kernel<<<TT, 256, 0, stream>>>(x, gate_w, gate_b, counts, tok, wgt);

  // routed GEMM1+SwiGLU: N=704 -> 11 n-tiles; up to 32 m-tiles; 16 experts
  gemm1_kernel<true><<<dim3(HH / 64, TT / 64, EE), 256, 0, stream>>>(
      x, w1, w3, act, counts, tok, HH, TT);

  // shared GEMM1+SwiGLU: N=1408 -> 22 n-tiles
  gemm1_kernel<false><<<dim3(HSS / 64, TT / 64, 1), 256, 0, stream>>>(
      x, ws1, ws3, acts, nullptr, nullptr, HSS, TT);

  // shared GEMM2 first: plain stores cover all of y (no memset needed)
  gemm2_kernel<false><<<dim3(DD / 128, TT / 64, 1), 256, 0, stream>>>(
      acts, ws2, y, nullptr, nullptr, nullptr, HSS, TT);

  // routed GEMM2: atomic accumulate with gate weights
  gemm2_kernel<true><<<dim3(DD / 128, TT / 64, EE), 256, 0, stream>>>(
      act, w2, y, counts, tok, wgt, HH, TT);
}

// Round 3
// 450.510 us; speedup vs baseline: 1.2475x; 1.2475x over previous
//
#include <hip/hip_runtime.h>
#include <hip/hip_bf16.h>
#include <math.h>

// ---------------- types ----------------
typedef __attribute__((ext_vector_type(4))) float   f32x4;
typedef __attribute__((ext_vector_type(8))) short   short8;
typedef __attribute__((ext_vector_type(8))) __bf16  bf16x8;

union SB8 { short8 s; bf16x8 b; };

__device__ __forceinline__ short f2bf(float f) {
  union { float f; unsigned u; } v; v.f = f;
  unsigned r = v.u + 0x7fffu + ((v.u >> 16) & 1u);   // RNE
  return (short)(r >> 16);
}

__device__ __forceinline__ short8 cvt8(f32x4 a, f32x4 b) {
  short8 r;
  r[0] = f2bf(a[0]); r[1] = f2bf(a[1]); r[2] = f2bf(a[2]); r[3] = f2bf(a[3]);
  r[4] = f2bf(b[0]); r[5] = f2bf(b[1]); r[6] = f2bf(b[2]); r[7] = f2bf(b[3]);
  return r;
}

// async global->LDS, 16B per lane; dest is wave-uniform base + lane*16
__device__ __forceinline__ void ldsload16(const short* g, short* l) {
  __builtin_amdgcn_global_load_lds(
      (const __attribute__((address_space(1))) unsigned int*)g,
      (__attribute__((address_space(3))) unsigned int*)l, 16, 0, 0);
}

// Problem constants
#define TT   2048
#define DD   1024        // K of gemm1
#define HH   704
#define HSS  1408
#define EE   16
#define CAP  2048

// bf16 segment offsets (elements) inside the big bf16 workspace buffer
#define O1  2097152ULL                    // x:  2048*1024
#define O2  13631488ULL                   // w1: 16*704*1024
#define O3  25165824ULL                   // w3
#define O4  36700160ULL                   // w2: 16*1024*704
#define O5  38141952ULL                   // ws1: 1408*1024
#define O6  39583744ULL                   // ws3
#define CVT_TOTAL 41025536ULL             // + ws2

// ---------------- fused fp32 -> bf16 convert ----------------
__global__ __launch_bounds__(256)
void cvt_all(const float* __restrict__ x,  const float* __restrict__ w1,
             const float* __restrict__ w3, const float* __restrict__ w2,
             const float* __restrict__ s1, const float* __restrict__ s3,
             const float* __restrict__ s2, short* __restrict__ dst)
{
  size_t i = ((size_t)blockIdx.x * 256 + threadIdx.x) * 8;
  const float* src;
  if      (i < O1) src = x  + i;
  else if (i < O2) src = w1 + (i - O1);
  else if (i < O3) src = w3 + (i - O2);
  else if (i < O4) src = w2 + (i - O3);
  else if (i < O5) src = s1 + (i - O4);
  else if (i < O6) src = s3 + (i - O5);
  else             src = s2 + (i - O6);
  f32x4 a = *(const f32x4*)src;
  f32x4 b = *(const f32x4*)(src + 4);
  *(short8*)(dst + i) = cvt8(a, b);
}

// ---------------- gate ----------------
__global__ __launch_bounds__(256)
void gate_kernel(const float* __restrict__ x, const float* __restrict__ gw,
                 const float* __restrict__ gb,
                 int* __restrict__ counts, int* __restrict__ tok,
                 float* __restrict__ wgt)
{
  const int t = blockIdx.x;
  const int tid = threadIdx.x;
  const float* xp = x + (size_t)t * DD;

  double acc[EE];
  #pragma unroll
  for (int e = 0; e < EE; e++) acc[e] = 0.0;

  for (int d = tid; d < DD; d += 256) {
    double xv = (double)xp[d];
    #pragma unroll
    for (int e = 0; e < EE; e++) acc[e] += xv * (double)gw[e * DD + d];
  }

  __shared__ double red[256 * EE];
  __shared__ double red2[16 * EE];
  __shared__ double logit[EE];
  #pragma unroll
  for (int e = 0; e < EE; e++) red[tid * EE + e] = acc[e];
  __syncthreads();
  {
    int e = tid & 15, i0 = tid >> 4;
    double s = 0.0;
    for (int i = i0; i < 256; i += 16) s += red[i * EE + e];
    red2[i0 * EE + e] = s;
  }
  __syncthreads();
  if (tid < EE) {
    double s = 0.0;
    for (int i = 0; i < 16; i++) s += red2[i * EE + tid];
    logit[tid] = s;
  }
  __syncthreads();

  if (tid == 0) {
    double sc[EE], r[EE];
    #pragma unroll
    for (int e = 0; e < EE; e++) {
      double sg = 1.0 / (1.0 + exp(-logit[e]));
      sc[e] = sg;
      r[e] = sg + (double)gb[e];
    }
    double gs[4];
    #pragma unroll
    for (int g = 0; g < 4; g++) {
      double m1 = -1e300, m2 = -1e300;
      for (int j = 0; j < 4; j++) {
        double v = r[g * 4 + j];
        if (v > m1) { m2 = m1; m1 = v; }
        else if (v > m2) { m2 = v; }
      }
      gs[g] = m1 + m2;
    }
    int g1 = 0, g2 = -1; double b1 = -1e300, b2 = -1e300;
    for (int g = 0; g < 4; g++) {
      if (gs[g] > b1) { b2 = b1; g2 = g1; b1 = gs[g]; g1 = g; }
      else if (gs[g] > b2) { b2 = gs[g]; g2 = g; }
    }
    bool keep[EE];
    #pragma unroll
    for (int e = 0; e < EE; e++) { int g = e >> 2; keep[e] = (g == g1) || (g == g2); }
    int idx[4]; double wv[4]; double wsum = 0.0;
    bool used[EE] = {false};
    for (int k = 0; k < 4; k++) {
      double best = -1e300; int bi = 0;
      for (int e = 0; e < EE; e++)
        if (keep[e] && !used[e] && r[e] > best) { best = r[e]; bi = e; }
      used[bi] = true; idx[k] = bi; wv[k] = sc[bi]; wsum += sc[bi];
    }
    double div = wsum < 1e-9 ? 1e-9 : wsum;
    for (int k = 0; k < 4; k++) {
      float w = (float)(wv[k] / div * 2.5446);
      int slot = atomicAdd(&counts[idx[k]], 1);
      tok[idx[k] * CAP + slot] = t;
      wgt[idx[k] * CAP + slot] = w;
    }
  }
}

// ---------------- prefix sum over expert counts ----------------
__global__ void scan_kernel(const int* __restrict__ counts, int* __restrict__ offs) {
  if (threadIdx.x == 0) {
    int s = 0;
    for (int e = 0; e < EE; e++) { offs[e] = s; s += counts[e]; }
    offs[EE] = s;
  }
}

// ---------------- GEMM1 + SwiGLU (bf16, global_load_lds) ----------------
// Block 256 thr / 4 waves. Tile M=128, N=128 (per matrix; dual B: W1,W3), BK=64.
// LDS per operand tile: 16 groups x (8 rows x 8 chunks of 16B), XOR-swizzled:
//   stage lane i in group g: holds row g*8+(i>>3), chunk (i&7)^(i>>3)
//   read chunk c of row r:   addr16 = (r>>3)*64 + (r&7)*8 + (c ^ (r&7))
// Wave w: all 8 m-tiles x n-tiles {2w, 2w+1} of each matrix -> 64 MFMA / iter.
template<bool GATHER>
__global__ __launch_bounds__(256, 2)
void gemm1_kernel(const short* __restrict__ xb, const short* __restrict__ W1g,
                  const short* __restrict__ W3g, short* __restrict__ act,
                  const int* __restrict__ counts, const int* __restrict__ offs,
                  const int* __restrict__ tok, const int N, const int T)
{
  const int e = GATHER ? blockIdx.z : 0;
  const int cnt = GATHER ? counts[e] : T;
  const int Mt = blockIdx.y, Nt = blockIdx.x;
  if (Mt * 128 >= cnt) return;
  const int rowbase = GATHER ? offs[e] : 0;

  const short* W1 = W1g + (size_t)e * N * DD;
  const short* W3 = W3g + (size_t)e * N * DD;

  __shared__ __align__(16) short lA[128 * 64];
  __shared__ __align__(16) short lB1[128 * 64];
  __shared__ __align__(16) short lB3[128 * 64];

  const int tid = threadIdx.x, lane = tid & 63, wv = tid >> 6;
  const int srow = lane >> 3, schunk = lane & 7, scg = schunk ^ srow;

  const short* pa[4]; const short* pb1[4]; const short* pb3[4];
  #pragma unroll
  for (int i = 0; i < 4; i++) {
    const int g = wv * 4 + i;
    int arow = Mt * 128 + g * 8 + srow;
    if (GATHER) {
      int slot = arow < cnt ? arow : cnt - 1;
      arow = tok[e * CAP + slot];
    }
    pa[i] = xb + (size_t)arow * DD + scg * 8;
    const int brow = Nt * 128 + g * 8 + srow;       // may overrun N=704; buffer padded by next tensor
    pb1[i] = W1 + (size_t)brow * DD + scg * 8;
    pb3[i] = W3 + (size_t)brow * DD + scg * 8;
  }

  f32x4 acc1[8][2], acc3[8][2];
  #pragma unroll
  for (int i = 0; i < 8; i++) {
    #pragma unroll
    for (int j = 0; j < 2; j++) {
      acc1[i][j] = (f32x4)0.f; acc3[i][j] = (f32x4)0.f;
    }
  }

  const int q = lane >> 4, r7 = lane & 7, hi = (lane & 15) >> 3;

  for (int kk = 0; kk < DD; kk += 64) {
    #pragma unroll
    for (int i = 0; i < 4; i++) {
      const int g = wv * 4 + i;
      ldsload16(pa[i] + kk,  lA  + g * 512);
      ldsload16(pb1[i] + kk, lB1 + g * 512);
      ldsload16(pb3[i] + kk, lB3 + g * 512);
    }
    __syncthreads();   // compiler drains vmcnt before barrier -> LDS valid
    #pragma unroll
    for (int kc = 0; kc < 2; kc++) {
      const int cx = (kc * 4 + q) ^ r7;
      SB8 b1f[2], b3f[2];
      #pragma unroll
      for (int ntl = 0; ntl < 2; ntl++) {
        const int a16 = ((wv * 2 + ntl) * 2 + hi) * 64 + r7 * 8 + cx;
        b1f[ntl].s = *(const short8*)(lB1 + a16 * 8);
        b3f[ntl].s = *(const short8*)(lB3 + a16 * 8);
      }
      #pragma unroll
      for (int mt = 0; mt < 8; mt++) {
        const int a16 = (2 * mt + hi) * 64 + r7 * 8 + cx;
        SB8 af; af.s = *(const short8*)(lA + a16 * 8);
        acc1[mt][0] = __builtin_amdgcn_mfma_f32_16x16x32_bf16(af.b, b1f[0].b, acc1[mt][0], 0, 0, 0);
        acc1[mt][1] = __builtin_amdgcn_mfma_f32_16x16x32_bf16(af.b, b1f[1].b, acc1[mt][1], 0, 0, 0);
        acc3[mt][0] = __builtin_amdgcn_mfma_f32_16x16x32_bf16(af.b, b3f[0].b, acc3[mt][0], 0, 0, 0);
        acc3[mt][1] = __builtin_amdgcn_mfma_f32_16x16x32_bf16(af.b, b3f[1].b, acc3[mt][1], 0, 0, 0);
      }
    }
    __syncthreads();   // readers done before next stage overwrites
  }

  const int quad = lane >> 4, lcol = lane & 15;
  #pragma unroll
  for (int mt = 0; mt < 8; mt++) {
    #pragma unroll
    for (int ntl = 0; ntl < 2; ntl++) {
      const int col = Nt * 128 + (wv * 2 + ntl) * 16 + lcol;
      #pragma unroll
      for (int rg = 0; rg < 4; rg++) {
        const int r = Mt * 128 + mt * 16 + quad * 4 + rg;
        if (r < cnt && col < N) {
          float g = acc1[mt][ntl][rg], u = acc3[mt][ntl][rg];
          float a = g / (1.f + __expf(-g)) * u;
          act[(size_t)(rowbase + r) * N + col] = f2bf(a);
        }
      }
    }
  }
}

// ---------------- GEMM2 (down proj, bf16) ----------------
// Tile M=128 x N=128, BK=64, same swizzled staging. Wave: 8 m-tiles x 2 n-tiles.
template<bool GATHER>
__global__ __launch_bounds__(256, 2)
void gemm2_kernel(const short* __restrict__ A, const short* __restrict__ Wg,
                  float* __restrict__ y, const int* __restrict__ counts,
                  const int* __restrict__ offs, const int* __restrict__ tok,
                  const float* __restrict__ wgt, const int Kd, const int T)
{
  const int e = GATHER ? blockIdx.z : 0;
  const int cnt = GATHER ? counts[e] : T;
  const int Mt = blockIdx.y, Nt = blockIdx.x;
  if (Mt * 128 >= cnt) return;
  const int rowbase = GATHER ? offs[e] : 0;

  const short* W = Wg + (size_t)e * DD * Kd;

  __shared__ __align__(16) short lA[128 * 64];
  __shared__ __align__(16) short lB[128 * 64];

  const int tid = threadIdx.x, lane = tid & 63, wv = tid >> 6;
  const int srow = lane >> 3, schunk = lane & 7, scg = schunk ^ srow;

  const short* pa[4]; const short* pb[4];
  #pragma unroll
  for (int i = 0; i < 4; i++) {
    const int g = wv * 4 + i;
    int arow = Mt * 128 + g * 8 + srow;
    if (GATHER) { if (arow >= cnt) arow = cnt - 1; }
    pa[i] = A + (size_t)(rowbase + arow) * Kd + scg * 8;
    const int brow = Nt * 128 + g * 8 + srow;       // <= 1023 always
    pb[i] = W + (size_t)brow * Kd + scg * 8;
  }

  f32x4 acc[8][2];
  #pragma unroll
  for (int i = 0; i < 8; i++) { acc[i][0] = (f32x4)0.f; acc[i][1] = (f32x4)0.f; }

  const int q = lane >> 4, r7 = lane & 7, hi = (lane & 15) >> 3;

  for (int kk = 0; kk < Kd; kk += 64) {
    #pragma unroll
    for (int i = 0; i < 4; i++) {
      const int g = wv * 4 + i;
      ldsload16(pa[i] + kk, lA + g * 512);
      ldsload16(pb[i] + kk, lB + g * 512);
    }
    __syncthreads();
    #pragma unroll
    for (int kc = 0; kc < 2; kc++) {
      const int cx = (kc * 4 + q) ^ r7;
      SB8 bf[2];
      #pragma unroll
      for (int ntl = 0; ntl < 2; ntl++) {
        const int a16 = ((wv * 2 + ntl) * 2 + hi) * 64 + r7 * 8 + cx;
        bf[ntl].s = *(const short8*)(lB + a16 * 8);
      }
      #pragma unroll
      for (int mt = 0; mt < 8; mt++) {
        const int a16 = (2 * mt + hi) * 64 + r7 * 8 + cx;
        SB8 af; af.s = *(const short8*)(lA + a16 * 8);
        acc[mt][0] = __builtin_amdgcn_mfma_f32_16x16x32_bf16(af.b, bf[0].b, acc[mt][0], 0, 0, 0);
        acc[mt][1] = __builtin_amdgcn_mfma_f32_16x16x32_bf16(af.b, bf[1].b, acc[mt][1], 0, 0, 0);
      }
    }
    __syncthreads();
  }

  const int quad = lane >> 4, lcol = lane & 15;
  #pragma unroll
  for (int mt = 0; mt < 8; mt++) {
    #pragma unroll
    for (int ntl = 0; ntl < 2; ntl++) {
      const int col = Nt * 128 + (wv * 2 + ntl) * 16 + lcol;
      #pragma unroll
      for (int rg = 0; rg < 4; rg++) {
        const int slot = Mt * 128 + mt * 16 + quad * 4 + rg;
        const float v = acc[mt][ntl][rg];
        if (GATHER) {
          if (slot < cnt) {
            const int t = tok[e * CAP + slot];
            const float w = wgt[e * CAP + slot];
            atomicAdd(&y[(size_t)t * DD + col], w * v);
          }
        } else {
          y[(size_t)slot * DD + col] = v;
        }
      }
    }
  }
}

// ---------------- launch ----------------
extern "C" void kernel_launch(void* const* d_in, const int* in_sizes, int n_in,
                              void* d_out, int out_size, void* d_ws, size_t ws_size,
                              hipStream_t stream) {
  const float* x      = (const float*)d_in[0];
  const float* gate_w = (const float*)d_in[1];
  const float* gate_b = (const float*)d_in[2];
  const float* w1     = (const float*)d_in[3];
  const float* w3     = (const float*)d_in[4];
  const float* w2     = (const float*)d_in[5];
  const float* ws1    = (const float*)d_in[6];
  const float* ws3    = (const float*)d_in[7];
  const float* ws2    = (const float*)d_in[8];
  float* y = (float*)d_out;

  char* ws = (char*)d_ws;
  // layout: counts@0 (64B), offs@64 (68B), tok@1024 (128KB), wgt@132096 (128KB),
  //         bf16 area @263168, act_r / act_s after. Total ~95 MB.
  int*   counts = (int*)ws;
  int*   offs   = (int*)(ws + 64);
  int*   tok    = (int*)(ws + 1024);
  float* wgt    = (float*)(ws + 1024 + (size_t)EE * CAP * 4);
  short* bf     = (short*)(ws + 263168);
  short* xb   = bf;
  short* w1b  = bf + O1;
  short* w3b  = bf + O2;
  short* w2b  = bf + O3;
  short* ws1b = bf + O4;
  short* ws3b = bf + O5;
  short* ws2b = bf + O6;
  short* act_r = bf + CVT_TOTAL;                 // [8192][704]
  short* act_s = act_r + (size_t)8192 * HH;      // [2048][1408]

  (void)hipMemsetAsync(counts, 0, 256, stream);

  gate_kernel<<<TT, 256, 0, stream>>>(x, gate_w, gate_b, counts, tok, wgt);
  scan_kernel<<<1, 64, 0, stream>>>(counts, offs);

  cvt_all<<<20032, 256, 0, stream>>>(x, w1, w3, w2, ws1, ws3, ws2, bf);

  // routed GEMM1+SwiGLU: N=704 -> 6 ragged n-tiles of 128
  gemm1_kernel<true><<<dim3(6, TT / 128, EE), 256, 0, stream>>>(
      xb, w1b, w3b, act_r, counts, offs, tok, HH, TT);

  // shared GEMM1+SwiGLU: N=1408 -> 11 n-tiles
  gemm1_kernel<false><<<dim3(HSS / 128, TT / 128, 1), 256, 0, stream>>>(
      xb, ws1b, ws3b, act_s, nullptr, nullptr, nullptr, HSS, TT);

  // shared GEMM2 first: plain stores cover all of y
  gemm2_kernel<false><<<dim3(DD / 128, TT / 128, 1), 256, 0, stream>>>(
      act_s, ws2b, y, nullptr, nullptr, nullptr, nullptr, HSS, TT);

  // routed GEMM2: atomic accumulate with gate weights
  gemm2_kernel<true><<<dim3(DD / 128, TT / 128, EE), 256, 0, stream>>>(
      act_r, w2b, y, counts, offs, tok, wgt, HH, TT);
}

// Round 4
// 388.407 us; speedup vs baseline: 1.4470x; 1.1599x over previous
//
#include <hip/hip_runtime.h>
#include <hip/hip_bf16.h>
#include <math.h>

// ---------------- types ----------------
typedef __attribute__((ext_vector_type(4))) float   f32x4;
typedef __attribute__((ext_vector_type(8))) short   short8;
typedef __attribute__((ext_vector_type(8))) __bf16  bf16x8;

union SB8 { short8 s; bf16x8 b; };

__device__ __forceinline__ short f2bf(float f) {
  union { float f; unsigned u; } v; v.f = f;
  unsigned r = v.u + 0x7fffu + ((v.u >> 16) & 1u);   // RNE
  return (short)(r >> 16);
}

__device__ __forceinline__ short8 cvt8(f32x4 a, f32x4 b) {
  short8 r;
  r[0] = f2bf(a[0]); r[1] = f2bf(a[1]); r[2] = f2bf(a[2]); r[3] = f2bf(a[3]);
  r[4] = f2bf(b[0]); r[5] = f2bf(b[1]); r[6] = f2bf(b[2]); r[7] = f2bf(b[3]);
  return r;
}

// async global->LDS, 16B per lane; dest is wave-uniform base + lane*16
__device__ __forceinline__ void ldsload16(const short* g, short* l) {
  __builtin_amdgcn_global_load_lds(
      (const __attribute__((address_space(1))) unsigned int*)g,
      (__attribute__((address_space(3))) unsigned int*)l, 16, 0, 0);
}

// Problem constants
#define TT   2048
#define DD   1024        // K of gemm1
#define HH   704
#define HSS  1408
#define EE   16
#define CAP  2048

// bf16 segment offsets (elements) inside the big bf16 workspace buffer
#define O1  2097152ULL                    // x:  2048*1024
#define O2  13631488ULL                   // w1: 16*704*1024
#define O3  25165824ULL                   // w3
#define O4  36700160ULL                   // w2: 16*1024*704
#define O5  38141952ULL                   // ws1: 1408*1024
#define O6  39583744ULL                   // ws3
#define CVT_TOTAL 41025536ULL             // + ws2

// ---------------- fused fp32 -> bf16 convert ----------------
__global__ __launch_bounds__(256)
void cvt_all(const float* __restrict__ x,  const float* __restrict__ w1,
             const float* __restrict__ w3, const float* __restrict__ w2,
             const float* __restrict__ s1, const float* __restrict__ s3,
             const float* __restrict__ s2, short* __restrict__ dst)
{
  size_t i = ((size_t)blockIdx.x * 256 + threadIdx.x) * 8;
  const float* src;
  if      (i < O1) src = x  + i;
  else if (i < O2) src = w1 + (i - O1);
  else if (i < O3) src = w3 + (i - O2);
  else if (i < O4) src = w2 + (i - O3);
  else if (i < O5) src = s1 + (i - O4);
  else if (i < O6) src = s3 + (i - O5);
  else             src = s2 + (i - O6);
  f32x4 a = *(const f32x4*)src;
  f32x4 b = *(const f32x4*)(src + 4);
  *(short8*)(dst + i) = cvt8(a, b);
}

// ---------------- gate ----------------
// One WAVE per token, no LDS. Lane L: expert e=L&15, d-part p=L>>4 (256 d's).
// fp64 dot products (deterministic), fp32 routing replicated on all lanes.
__global__ __launch_bounds__(256)
void gate_kernel(const float* __restrict__ x, const float* __restrict__ gw,
                 const float* __restrict__ gb,
                 int* __restrict__ counts, int* __restrict__ tok,
                 float* __restrict__ wgt)
{
  const int lane = threadIdx.x & 63;
  const int wid  = threadIdx.x >> 6;
  const int t    = blockIdx.x * 4 + wid;
  const int e    = lane & 15;
  const int p    = lane >> 4;

  const float* xp = x + (size_t)t * DD + p * 256;
  const float* gp = gw + (size_t)e * DD + p * 256;

  double acc = 0.0;
  #pragma unroll 8
  for (int i = 0; i < 64; i++) {
    f32x4 xa = *(const f32x4*)(xp + i * 4);
    f32x4 ga = *(const f32x4*)(gp + i * 4);
    acc += (double)xa[0] * (double)ga[0];
    acc += (double)xa[1] * (double)ga[1];
    acc += (double)xa[2] * (double)ga[2];
    acc += (double)xa[3] * (double)ga[3];
  }
  // reduce over the 4 parts (lanes e, e+16, e+32, e+48)
  acc += __shfl_xor(acc, 16);
  acc += __shfl_xor(acc, 32);
  float accf = (float)acc;

  // broadcast 16 logits to all lanes; replicate routing (uniform, no divergence)
  float lf[EE], sc[EE], r[EE];
  #pragma unroll
  for (int j = 0; j < EE; j++) lf[j] = __shfl(accf, j);
  #pragma unroll
  for (int j = 0; j < EE; j++) {
    sc[j] = 1.f / (1.f + expf(-lf[j]));
    r[j] = sc[j] + gb[j];
  }
  // group scores = sum of top-2 within each group of 4
  float gs[4];
  #pragma unroll
  for (int g = 0; g < 4; g++) {
    float m1 = -1e30f, m2 = -1e30f;
    #pragma unroll
    for (int j = 0; j < 4; j++) {
      float v = r[g * 4 + j];
      if (v > m1) { m2 = m1; m1 = v; }
      else if (v > m2) { m2 = v; }
    }
    gs[g] = m1 + m2;
  }
  // top-2 groups (ties -> lower index)
  int g1 = 0, g2 = -1; float b1 = -1e30f, b2 = -1e30f;
  #pragma unroll
  for (int g = 0; g < 4; g++) {
    if (gs[g] > b1) { b2 = b1; g2 = g1; b1 = gs[g]; g1 = g; }
    else if (gs[g] > b2) { b2 = gs[g]; g2 = g; }
  }
  // top-4 experts among kept groups (stable: strict >, lowest index wins)
  int idx[4]; float wv[4]; float wsum = 0.f;
  unsigned used = 0;
  #pragma unroll
  for (int k = 0; k < 4; k++) {
    float best = -1e30f; int bi = 0;
    #pragma unroll
    for (int j = 0; j < EE; j++) {
      int g = j >> 2;
      bool keep = (g == g1) || (g == g2);
      if (keep && !((used >> j) & 1) && r[j] > best) { best = r[j]; bi = j; }
    }
    used |= 1u << bi; idx[k] = bi; wv[k] = sc[bi]; wsum += sc[bi];
  }
  float div = wsum < 1e-9f ? 1e-9f : wsum;
  if (lane < 4) {
    float w = wv[lane] / div * 2.5446f;
    int slot = atomicAdd(&counts[idx[lane]], 1);
    tok[idx[lane] * CAP + slot] = t;
    wgt[idx[lane] * CAP + slot] = w;
  }
}

// ---------------- prefix sum over expert counts ----------------
__global__ void scan_kernel(const int* __restrict__ counts, int* __restrict__ offs) {
  if (threadIdx.x == 0) {
    int s = 0;
    for (int e = 0; e < EE; e++) { offs[e] = s; s += counts[e]; }
    offs[EE] = s;
  }
}

// ---------------- GEMM1 + SwiGLU (bf16, global_load_lds) ----------------
// Block 256 thr / 4 waves. Tile M=128, N=128 (per matrix; dual B: W1,W3), BK=64.
// LDS per operand tile: 16 groups x (8 rows x 8 chunks of 16B), XOR-swizzled:
//   stage lane i in group g: holds row g*8+(i>>3), chunk (i&7)^(i>>3)
//   read chunk c of row r:   addr16 = (r>>3)*64 + (r&7)*8 + (c ^ (r&7))
// Wave w: all 8 m-tiles x n-tiles {2w, 2w+1} of each matrix -> 64 MFMA / iter.
template<bool GATHER>
__global__ __launch_bounds__(256, 2)
void gemm1_kernel(const short* __restrict__ xb, const short* __restrict__ W1g,
                  const short* __restrict__ W3g, short* __restrict__ act,
                  const int* __restrict__ counts, const int* __restrict__ offs,
                  const int* __restrict__ tok, const int N, const int T)
{
  const int e = GATHER ? blockIdx.z : 0;
  const int cnt = GATHER ? counts[e] : T;
  const int Mt = blockIdx.y, Nt = blockIdx.x;
  if (Mt * 128 >= cnt) return;
  const int rowbase = GATHER ? offs[e] : 0;

  const short* W1 = W1g + (size_t)e * N * DD;
  const short* W3 = W3g + (size_t)e * N * DD;

  __shared__ __align__(16) short lA[128 * 64];
  __shared__ __align__(16) short lB1[128 * 64];
  __shared__ __align__(16) short lB3[128 * 64];

  const int tid = threadIdx.x, lane = tid & 63, wv = tid >> 6;
  const int srow = lane >> 3, schunk = lane & 7, scg = schunk ^ srow;

  const short* pa[4]; const short* pb1[4]; const short* pb3[4];
  #pragma unroll
  for (int i = 0; i < 4; i++) {
    const int g = wv * 4 + i;
    int arow = Mt * 128 + g * 8 + srow;
    if (GATHER) {
      int slot = arow < cnt ? arow : cnt - 1;
      arow = tok[e * CAP + slot];
    }
    pa[i] = xb + (size_t)arow * DD + scg * 8;
    const int brow = Nt * 128 + g * 8 + srow;       // may overrun N=704; buffer padded by next tensor
    pb1[i] = W1 + (size_t)brow * DD + scg * 8;
    pb3[i] = W3 + (size_t)brow * DD + scg * 8;
  }

  f32x4 acc1[8][2], acc3[8][2];
  #pragma unroll
  for (int i = 0; i < 8; i++) {
    #pragma unroll
    for (int j = 0; j < 2; j++) {
      acc1[i][j] = (f32x4)0.f; acc3[i][j] = (f32x4)0.f;
    }
  }

  const int q = lane >> 4, r7 = lane & 7, hi = (lane & 15) >> 3;

  for (int kk = 0; kk < DD; kk += 64) {
    #pragma unroll
    for (int i = 0; i < 4; i++) {
      const int g = wv * 4 + i;
      ldsload16(pa[i] + kk,  lA  + g * 512);
      ldsload16(pb1[i] + kk, lB1 + g * 512);
      ldsload16(pb3[i] + kk, lB3 + g * 512);
    }
    __syncthreads();   // compiler drains vmcnt before barrier -> LDS valid
    #pragma unroll
    for (int kc = 0; kc < 2; kc++) {
      const int cx = (kc * 4 + q) ^ r7;
      SB8 b1f[2], b3f[2];
      #pragma unroll
      for (int ntl = 0; ntl < 2; ntl++) {
        const int a16 = ((wv * 2 + ntl) * 2 + hi) * 64 + r7 * 8 + cx;
        b1f[ntl].s = *(const short8*)(lB1 + a16 * 8);
        b3f[ntl].s = *(const short8*)(lB3 + a16 * 8);
      }
      #pragma unroll
      for (int mt = 0; mt < 8; mt++) {
        const int a16 = (2 * mt + hi) * 64 + r7 * 8 + cx;
        SB8 af; af.s = *(const short8*)(lA + a16 * 8);
        acc1[mt][0] = __builtin_amdgcn_mfma_f32_16x16x32_bf16(af.b, b1f[0].b, acc1[mt][0], 0, 0, 0);
        acc1[mt][1] = __builtin_amdgcn_mfma_f32_16x16x32_bf16(af.b, b1f[1].b, acc1[mt][1], 0, 0, 0);
        acc3[mt][0] = __builtin_amdgcn_mfma_f32_16x16x32_bf16(af.b, b3f[0].b, acc3[mt][0], 0, 0, 0);
        acc3[mt][1] = __builtin_amdgcn_mfma_f32_16x16x32_bf16(af.b, b3f[1].b, acc3[mt][1], 0, 0, 0);
      }
    }
    __syncthreads();   // readers done before next stage overwrites
  }

  const int quad = lane >> 4, lcol = lane & 15;
  #pragma unroll
  for (int mt = 0; mt < 8; mt++) {
    #pragma unroll
    for (int ntl = 0; ntl < 2; ntl++) {
      const int col = Nt * 128 + (wv * 2 + ntl) * 16 + lcol;
      #pragma unroll
      for (int rg = 0; rg < 4; rg++) {
        const int r = Mt * 128 + mt * 16 + quad * 4 + rg;
        if (r < cnt && col < N) {
          float g = acc1[mt][ntl][rg], u = acc3[mt][ntl][rg];
          float a = g / (1.f + __expf(-g)) * u;
          act[(size_t)(rowbase + r) * N + col] = f2bf(a);
        }
      }
    }
  }
}

// ---------------- GEMM2 (down proj, bf16) ----------------
// Tile M=128 x N=128, BK=64, same swizzled staging. Wave: 8 m-tiles x 2 n-tiles.
template<bool GATHER>
__global__ __launch_bounds__(256, 2)
void gemm2_kernel(const short* __restrict__ A, const short* __restrict__ Wg,
                  float* __restrict__ y, const int* __restrict__ counts,
                  const int* __restrict__ offs, const int* __restrict__ tok,
                  const float* __restrict__ wgt, const int Kd, const int T)
{
  const int e = GATHER ? blockIdx.z : 0;
  const int cnt = GATHER ? counts[e] : T;
  const int Mt = blockIdx.y, Nt = blockIdx.x;
  if (Mt * 128 >= cnt) return;
  const int rowbase = GATHER ? offs[e] : 0;

  const short* W = Wg + (size_t)e * DD * Kd;

  __shared__ __align__(16) short lA[128 * 64];
  __shared__ __align__(16) short lB[128 * 64];

  const int tid = threadIdx.x, lane = tid & 63, wv = tid >> 6;
  const int srow = lane >> 3, schunk = lane & 7, scg = schunk ^ srow;

  const short* pa[4]; const short* pb[4];
  #pragma unroll
  for (int i = 0; i < 4; i++) {
    const int g = wv * 4 + i;
    int arow = Mt * 128 + g * 8 + srow;
    if (GATHER) { if (arow >= cnt) arow = cnt - 1; }
    pa[i] = A + (size_t)(rowbase + arow) * Kd + scg * 8;
    const int brow = Nt * 128 + g * 8 + srow;       // <= 1023 always
    pb[i] = W + (size_t)brow * Kd + scg * 8;
  }

  f32x4 acc[8][2];
  #pragma unroll
  for (int i = 0; i < 8; i++) { acc[i][0] = (f32x4)0.f; acc[i][1] = (f32x4)0.f; }

  const int q = lane >> 4, r7 = lane & 7, hi = (lane & 15) >> 3;

  for (int kk = 0; kk < Kd; kk += 64) {
    #pragma unroll
    for (int i = 0; i < 4; i++) {
      const int g = wv * 4 + i;
      ldsload16(pa[i] + kk, lA + g * 512);
      ldsload16(pb[i] + kk, lB + g * 512);
    }
    __syncthreads();
    #pragma unroll
    for (int kc = 0; kc < 2; kc++) {
      const int cx = (kc * 4 + q) ^ r7;
      SB8 bf[2];
      #pragma unroll
      for (int ntl = 0; ntl < 2; ntl++) {
        const int a16 = ((wv * 2 + ntl) * 2 + hi) * 64 + r7 * 8 + cx;
        bf[ntl].s = *(const short8*)(lB + a16 * 8);
      }
      #pragma unroll
      for (int mt = 0; mt < 8; mt++) {
        const int a16 = (2 * mt + hi) * 64 + r7 * 8 + cx;
        SB8 af; af.s = *(const short8*)(lA + a16 * 8);
        acc[mt][0] = __builtin_amdgcn_mfma_f32_16x16x32_bf16(af.b, bf[0].b, acc[mt][0], 0, 0, 0);
        acc[mt][1] = __builtin_amdgcn_mfma_f32_16x16x32_bf16(af.b, bf[1].b, acc[mt][1], 0, 0, 0);
      }
    }
    __syncthreads();
  }

  const int quad = lane >> 4, lcol = lane & 15;
  #pragma unroll
  for (int mt = 0; mt < 8; mt++) {
    #pragma unroll
    for (int ntl = 0; ntl < 2; ntl++) {
      const int col = Nt * 128 + (wv * 2 + ntl) * 16 + lcol;
      #pragma unroll
      for (int rg = 0; rg < 4; rg++) {
        const int slot = Mt * 128 + mt * 16 + quad * 4 + rg;
        const float v = acc[mt][ntl][rg];
        if (GATHER) {
          if (slot < cnt) {
            const int t = tok[e * CAP + slot];
            const float w = wgt[e * CAP + slot];
            atomicAdd(&y[(size_t)t * DD + col], w * v);
          }
        } else {
          y[(size_t)slot * DD + col] = v;
        }
      }
    }
  }
}

// ---------------- launch ----------------
extern "C" void kernel_launch(void* const* d_in, const int* in_sizes, int n_in,
                              void* d_out, int out_size, void* d_ws, size_t ws_size,
                              hipStream_t stream) {
  const float* x      = (const float*)d_in[0];
  const float* gate_w = (const float*)d_in[1];
  const float* gate_b = (const float*)d_in[2];
  const float* w1     = (const float*)d_in[3];
  const float* w3     = (const float*)d_in[4];
  const float* w2     = (const float*)d_in[5];
  const float* ws1    = (const float*)d_in[6];
  const float* ws3    = (const float*)d_in[7];
  const float* ws2    = (const float*)d_in[8];
  float* y = (float*)d_out;

  char* ws = (char*)d_ws;
  // layout: counts@0 (64B), offs@64 (68B), tok@1024 (128KB), wgt@132096 (128KB),
  //         bf16 area @263168, act_r / act_s after. Total ~95 MB.
  int*   counts = (int*)ws;
  int*   offs   = (int*)(ws + 64);
  int*   tok    = (int*)(ws + 1024);
  float* wgt    = (float*)(ws + 1024 + (size_t)EE * CAP * 4);
  short* bf     = (short*)(ws + 263168);
  short* xb   = bf;
  short* w1b  = bf + O1;
  short* w3b  = bf + O2;
  short* w2b  = bf + O3;
  short* ws1b = bf + O4;
  short* ws3b = bf + O5;
  short* ws2b = bf + O6;
  short* act_r = bf + CVT_TOTAL;                 // [8192][704]
  short* act_s = act_r + (size_t)8192 * HH;      // [2048][1408]

  (void)hipMemsetAsync(counts, 0, 256, stream);

  gate_kernel<<<TT / 4, 256, 0, stream>>>(x, gate_w, gate_b, counts, tok, wgt);
  scan_kernel<<<1, 64, 0, stream>>>(counts, offs);

  cvt_all<<<20032, 256, 0, stream>>>(x, w1, w3, w2, ws1, ws3, ws2, bf);

  // routed GEMM1+SwiGLU: N=704 -> 6 ragged n-tiles of 128
  gemm1_kernel<true><<<dim3(6, TT / 128, EE), 256, 0, stream>>>(
      xb, w1b, w3b, act_r, counts, offs, tok, HH, TT);

  // shared GEMM1+SwiGLU: N=1408 -> 11 n-tiles
  gemm1_kernel<false><<<dim3(HSS / 128, TT / 128, 1), 256, 0, stream>>>(
      xb, ws1b, ws3b, act_s, nullptr, nullptr, nullptr, HSS, TT);

  // shared GEMM2 first: plain stores cover all of y
  gemm2_kernel<false><<<dim3(DD / 128, TT / 128, 1), 256, 0, stream>>>(
      act_s, ws2b, y, nullptr, nullptr, nullptr, nullptr, HSS, TT);

  // routed GEMM2: atomic accumulate with gate weights
  gemm2_kernel<true><<<dim3(DD / 128, TT / 128, EE), 256, 0, stream>>>(
      act_r, w2b, y, counts, offs, tok, wgt, HH, TT);
}

// Round 5
// 355.171 us; speedup vs baseline: 1.5824x; 1.0936x over previous
//
#include <hip/hip_runtime.h>
#include <hip/hip_bf16.h>
#include <math.h>

// ---------------- types ----------------
typedef __attribute__((ext_vector_type(4))) float   f32x4;
typedef __attribute__((ext_vector_type(8))) short   short8;
typedef __attribute__((ext_vector_type(8))) __bf16  bf16x8;

union SB8 { short8 s; bf16x8 b; };

__device__ __forceinline__ short f2bf(float f) {
  union { float f; unsigned u; } v; v.f = f;
  unsigned r = v.u + 0x7fffu + ((v.u >> 16) & 1u);   // RNE
  return (short)(r >> 16);
}

__device__ __forceinline__ short8 cvt8(f32x4 a, f32x4 b) {
  short8 r;
  r[0] = f2bf(a[0]); r[1] = f2bf(a[1]); r[2] = f2bf(a[2]); r[3] = f2bf(a[3]);
  r[4] = f2bf(b[0]); r[5] = f2bf(b[1]); r[6] = f2bf(b[2]); r[7] = f2bf(b[3]);
  return r;
}

// async global->LDS, 16B per lane; dest is wave-uniform base + lane*16
__device__ __forceinline__ void ldsload16(const short* g, short* l) {
  __builtin_amdgcn_global_load_lds(
      (const __attribute__((address_space(1))) unsigned int*)g,
      (__attribute__((address_space(3))) unsigned int*)l, 16, 0, 0);
}

// Problem constants
#define TT   2048
#define DD   1024        // K of gemm1, N of gemm2
#define HH   704
#define HSS  1408
#define EE   16
#define CAP  2048

// bf16 segment offsets (elements) inside the big bf16 workspace buffer
#define O1  2097152ULL                    // x:  2048*1024
#define O2  13631488ULL                   // w1: 16*704*1024
#define O3  25165824ULL                   // w3
#define O4  36700160ULL                   // w2: 16*1024*704
#define O5  38141952ULL                   // ws1: 1408*1024
#define O6  39583744ULL                   // ws3
#define CVT_TOTAL 41025536ULL             // + ws2
#define CVT_BLOCKS 5008                   // CVT_TOTAL / 8192

// ---------------- fused fp32->bf16 convert + gate ----------------
// Blocks [0, CVT_BLOCKS): convert 8192 contiguous elements (4 slabs of 2048,
//   each slab = 256 threads x 8 elems, coalesced; 8 outstanding loads/thread).
// Blocks [CVT_BLOCKS, CVT_BLOCKS+512): gate — one wave per token, no LDS.
__global__ __launch_bounds__(256)
void cvt_gate(const float* __restrict__ x,  const float* __restrict__ w1,
              const float* __restrict__ w3, const float* __restrict__ w2,
              const float* __restrict__ s1, const float* __restrict__ s3,
              const float* __restrict__ s2, short* __restrict__ dst,
              const float* __restrict__ gw, const float* __restrict__ gb,
              int* __restrict__ counts, int* __restrict__ tok,
              float* __restrict__ wgt, int* __restrict__ eslot)
{
  if (blockIdx.x < CVT_BLOCKS) {
    const size_t blk = (size_t)blockIdx.x * 8192;
    #pragma unroll
    for (int k = 0; k < 4; k++) {
      size_t i = blk + (size_t)k * 2048 + (size_t)threadIdx.x * 8;
      const float* src;
      if      (i < O1) src = x  + i;
      else if (i < O2) src = w1 + (i - O1);
      else if (i < O3) src = w3 + (i - O2);
      else if (i < O4) src = w2 + (i - O3);
      else if (i < O5) src = s1 + (i - O4);
      else if (i < O6) src = s3 + (i - O5);
      else             src = s2 + (i - O6);
      f32x4 a = *(const f32x4*)src;
      f32x4 b = *(const f32x4*)(src + 4);
      *(short8*)(dst + i) = cvt8(a, b);
    }
    return;
  }

  // ---- gate part ----
  const int lane = threadIdx.x & 63;
  const int wid  = threadIdx.x >> 6;
  const int t    = (blockIdx.x - CVT_BLOCKS) * 4 + wid;
  const int e    = lane & 15;
  const int p    = lane >> 4;

  const float* xp = x + (size_t)t * DD + p * 256;
  const float* gp = gw + (size_t)e * DD + p * 256;

  double acc = 0.0;
  #pragma unroll 8
  for (int i = 0; i < 64; i++) {
    f32x4 xa = *(const f32x4*)(xp + i * 4);
    f32x4 ga = *(const f32x4*)(gp + i * 4);
    acc += (double)xa[0] * (double)ga[0];
    acc += (double)xa[1] * (double)ga[1];
    acc += (double)xa[2] * (double)ga[2];
    acc += (double)xa[3] * (double)ga[3];
  }
  acc += __shfl_xor(acc, 16);
  acc += __shfl_xor(acc, 32);
  float accf = (float)acc;

  float lf[EE], sc[EE], r[EE];
  #pragma unroll
  for (int j = 0; j < EE; j++) lf[j] = __shfl(accf, j);
  #pragma unroll
  for (int j = 0; j < EE; j++) {
    sc[j] = 1.f / (1.f + expf(-lf[j]));
    r[j] = sc[j] + gb[j];
  }
  float gs[4];
  #pragma unroll
  for (int g = 0; g < 4; g++) {
    float m1 = -1e30f, m2 = -1e30f;
    #pragma unroll
    for (int j = 0; j < 4; j++) {
      float v = r[g * 4 + j];
      if (v > m1) { m2 = m1; m1 = v; }
      else if (v > m2) { m2 = v; }
    }
    gs[g] = m1 + m2;
  }
  int g1 = 0, g2 = -1; float b1 = -1e30f, b2 = -1e30f;
  #pragma unroll
  for (int g = 0; g < 4; g++) {
    if (gs[g] > b1) { b2 = b1; g2 = g1; b1 = gs[g]; g1 = g; }
    else if (gs[g] > b2) { b2 = gs[g]; g2 = g; }
  }
  int idx[4]; float wv[4]; float wsum = 0.f;
  unsigned used = 0;
  #pragma unroll
  for (int k = 0; k < 4; k++) {
    float best = -1e30f; int bi = 0;
    #pragma unroll
    for (int j = 0; j < EE; j++) {
      int g = j >> 2;
      bool keep = (g == g1) || (g == g2);
      if (keep && !((used >> j) & 1) && r[j] > best) { best = r[j]; bi = j; }
    }
    used |= 1u << bi; idx[k] = bi; wv[k] = sc[bi]; wsum += sc[bi];
  }
  float div = wsum < 1e-9f ? 1e-9f : wsum;
  if (lane < 4) {
    float w = wv[lane] / div * 2.5446f;
    int slot = atomicAdd(&counts[idx[lane]], 1);
    tok[idx[lane] * CAP + slot] = t;
    wgt[idx[lane] * CAP + slot] = w;
    eslot[t * 4 + lane] = (idx[lane] << 16) | slot;
  }
}

// ---------------- merged GEMM1 + SwiGLU (bf16, global_load_lds) ----------------
// grid (11, 16, 17): z<16 -> routed expert z (N=704, Nt<6, gathered A);
//                    z==16 -> shared FFN (N=1408).
// Tile M=128, N=128 (dual B: W1,W3), BK=64. XOR-swizzled LDS (see r3 notes).
__global__ __launch_bounds__(256, 2)
void gemm1_merged(const short* __restrict__ xb, const short* __restrict__ w1b,
                  const short* __restrict__ w3b, const short* __restrict__ ws1b,
                  const short* __restrict__ ws3b, short* __restrict__ act_r,
                  short* __restrict__ act_s, const int* __restrict__ counts,
                  const int* __restrict__ tok)
{
  const int z = blockIdx.z;
  const bool routed = (z < EE);
  const int Mt = blockIdx.y, Nt = blockIdx.x;

  int cnt, N, rowbase = 0;
  const short *W1, *W3;
  short* act;
  if (routed) {
    if (Nt >= 6) return;
    cnt = counts[z];
    if (Mt * 128 >= cnt) return;
    int rb = 0;
    for (int i = 0; i < z; i++) rb += counts[i];
    rowbase = rb;
    N = HH;
    W1 = w1b + (size_t)z * HH * DD;
    W3 = w3b + (size_t)z * HH * DD;
    act = act_r;
  } else {
    cnt = TT; N = HSS; W1 = ws1b; W3 = ws3b; act = act_s;
  }

  __shared__ __align__(16) short lA[128 * 64];
  __shared__ __align__(16) short lB1[128 * 64];
  __shared__ __align__(16) short lB3[128 * 64];

  const int tid = threadIdx.x, lane = tid & 63, wv = tid >> 6;
  const int srow = lane >> 3, schunk = lane & 7, scg = schunk ^ srow;

  const short* pa[4]; const short* pb1[4]; const short* pb3[4];
  #pragma unroll
  for (int i = 0; i < 4; i++) {
    const int g = wv * 4 + i;
    int arow = Mt * 128 + g * 8 + srow;
    if (routed) {
      int slot = arow < cnt ? arow : cnt - 1;
      arow = tok[z * CAP + slot];
    }
    pa[i] = xb + (size_t)arow * DD + scg * 8;
    const int brow = Nt * 128 + g * 8 + srow;  // routed overrun reads next segment: harmless
    pb1[i] = W1 + (size_t)brow * DD + scg * 8;
    pb3[i] = W3 + (size_t)brow * DD + scg * 8;
  }

  f32x4 acc1[8][2], acc3[8][2];
  #pragma unroll
  for (int i = 0; i < 8; i++) {
    #pragma unroll
    for (int j = 0; j < 2; j++) { acc1[i][j] = (f32x4)0.f; acc3[i][j] = (f32x4)0.f; }
  }

  const int q = lane >> 4, r7 = lane & 7, hi = (lane & 15) >> 3;

  for (int kk = 0; kk < DD; kk += 64) {
    #pragma unroll
    for (int i = 0; i < 4; i++) {
      const int g = wv * 4 + i;
      ldsload16(pa[i] + kk,  lA  + g * 512);
      ldsload16(pb1[i] + kk, lB1 + g * 512);
      ldsload16(pb3[i] + kk, lB3 + g * 512);
    }
    __syncthreads();
    #pragma unroll
    for (int kc = 0; kc < 2; kc++) {
      const int cx = (kc * 4 + q) ^ r7;
      SB8 b1f[2], b3f[2];
      #pragma unroll
      for (int ntl = 0; ntl < 2; ntl++) {
        const int a16 = ((wv * 2 + ntl) * 2 + hi) * 64 + r7 * 8 + cx;
        b1f[ntl].s = *(const short8*)(lB1 + a16 * 8);
        b3f[ntl].s = *(const short8*)(lB3 + a16 * 8);
      }
      #pragma unroll
      for (int mt = 0; mt < 8; mt++) {
        const int a16 = (2 * mt + hi) * 64 + r7 * 8 + cx;
        SB8 af; af.s = *(const short8*)(lA + a16 * 8);
        acc1[mt][0] = __builtin_amdgcn_mfma_f32_16x16x32_bf16(af.b, b1f[0].b, acc1[mt][0], 0, 0, 0);
        acc1[mt][1] = __builtin_amdgcn_mfma_f32_16x16x32_bf16(af.b, b1f[1].b, acc1[mt][1], 0, 0, 0);
        acc3[mt][0] = __builtin_amdgcn_mfma_f32_16x16x32_bf16(af.b, b3f[0].b, acc3[mt][0], 0, 0, 0);
        acc3[mt][1] = __builtin_amdgcn_mfma_f32_16x16x32_bf16(af.b, b3f[1].b, acc3[mt][1], 0, 0, 0);
      }
    }
    __syncthreads();
  }

  const int quad = lane >> 4, lcol = lane & 15;
  #pragma unroll
  for (int mt = 0; mt < 8; mt++) {
    #pragma unroll
    for (int ntl = 0; ntl < 2; ntl++) {
      const int col = Nt * 128 + (wv * 2 + ntl) * 16 + lcol;
      #pragma unroll
      for (int rg = 0; rg < 4; rg++) {
        const int r = Mt * 128 + mt * 16 + quad * 4 + rg;
        if (r < cnt && col < N) {
          float g = acc1[mt][ntl][rg], u = acc3[mt][ntl][rg];
          float a = g / (1.f + __expf(-g)) * u;
          act[(size_t)(rowbase + r) * N + col] = f2bf(a);
        }
      }
    }
  }
}

// ---------------- merged GEMM2 (down proj, bf16) ----------------
// grid (8, 16, 17): z<16 -> routed expert z (K=704): weighted fp32 store to
//   compact outr (NO atomics); z==16 -> shared (K=1408): plain store to y.
__global__ __launch_bounds__(256, 2)
void gemm2_merged(const short* __restrict__ act_r, const short* __restrict__ act_s,
                  const short* __restrict__ w2b, const short* __restrict__ ws2b,
                  float* __restrict__ y, float* __restrict__ outr,
                  const int* __restrict__ counts, const float* __restrict__ wgt)
{
  const int z = blockIdx.z;
  const bool routed = (z < EE);
  const int Mt = blockIdx.y, Nt = blockIdx.x;

  int cnt, Kd, rowbase = 0;
  const short *A, *W;
  if (routed) {
    cnt = counts[z];
    if (Mt * 128 >= cnt) return;
    int rb = 0;
    for (int i = 0; i < z; i++) rb += counts[i];
    rowbase = rb;
    Kd = HH;
    A = act_r + (size_t)rowbase * HH;
    W = w2b + (size_t)z * DD * HH;
  } else {
    cnt = TT; Kd = HSS; A = act_s; W = ws2b;
  }

  __shared__ __align__(16) short lA[128 * 64];
  __shared__ __align__(16) short lB[128 * 64];

  const int tid = threadIdx.x, lane = tid & 63, wv = tid >> 6;
  const int srow = lane >> 3, schunk = lane & 7, scg = schunk ^ srow;

  const short* pa[4]; const short* pb[4];
  #pragma unroll
  for (int i = 0; i < 4; i++) {
    const int g = wv * 4 + i;
    int arow = Mt * 128 + g * 8 + srow;
    if (arow >= cnt) arow = cnt - 1;
    pa[i] = A + (size_t)arow * Kd + scg * 8;
    const int brow = Nt * 128 + g * 8 + srow;   // <= 1023 always
    pb[i] = W + (size_t)brow * Kd + scg * 8;
  }

  f32x4 acc[8][2];
  #pragma unroll
  for (int i = 0; i < 8; i++) { acc[i][0] = (f32x4)0.f; acc[i][1] = (f32x4)0.f; }

  const int q = lane >> 4, r7 = lane & 7, hi = (lane & 15) >> 3;

  for (int kk = 0; kk < Kd; kk += 64) {
    #pragma unroll
    for (int i = 0; i < 4; i++) {
      const int g = wv * 4 + i;
      ldsload16(pa[i] + kk, lA + g * 512);
      ldsload16(pb[i] + kk, lB + g * 512);
    }
    __syncthreads();
    #pragma unroll
    for (int kc = 0; kc < 2; kc++) {
      const int cx = (kc * 4 + q) ^ r7;
      SB8 bf[2];
      #pragma unroll
      for (int ntl = 0; ntl < 2; ntl++) {
        const int a16 = ((wv * 2 + ntl) * 2 + hi) * 64 + r7 * 8 + cx;
        bf[ntl].s = *(const short8*)(lB + a16 * 8);
      }
      #pragma unroll
      for (int mt = 0; mt < 8; mt++) {
        const int a16 = (2 * mt + hi) * 64 + r7 * 8 + cx;
        SB8 af; af.s = *(const short8*)(lA + a16 * 8);
        acc[mt][0] = __builtin_amdgcn_mfma_f32_16x16x32_bf16(af.b, bf[0].b, acc[mt][0], 0, 0, 0);
        acc[mt][1] = __builtin_amdgcn_mfma_f32_16x16x32_bf16(af.b, bf[1].b, acc[mt][1], 0, 0, 0);
      }
    }
    __syncthreads();
  }

  const int quad = lane >> 4, lcol = lane & 15;
  #pragma unroll
  for (int mt = 0; mt < 8; mt++) {
    #pragma unroll
    for (int ntl = 0; ntl < 2; ntl++) {
      const int col = Nt * 128 + (wv * 2 + ntl) * 16 + lcol;
      #pragma unroll
      for (int rg = 0; rg < 4; rg++) {
        const int slot = Mt * 128 + mt * 16 + quad * 4 + rg;
        const float v = acc[mt][ntl][rg];
        if (routed) {
          if (slot < cnt) {
            const float w = wgt[z * CAP + slot];
            outr[(size_t)(rowbase + slot) * DD + col] = w * v;
          }
        } else {
          y[(size_t)slot * DD + col] = v;
        }
      }
    }
  }
}

// ---------------- combine: y[t] += sum_k outr[offs[e_k]+slot_k] ----------------
__global__ __launch_bounds__(256)
void combine_kernel(float* __restrict__ y, const float* __restrict__ outr,
                    const int* __restrict__ eslot, const int* __restrict__ counts)
{
  const int t = blockIdx.x;
  const int d = threadIdx.x * 4;

  int offs[EE];
  int s = 0;
  #pragma unroll
  for (int i = 0; i < EE; i++) { offs[i] = s; s += counts[i]; }

  f32x4 accv = *(f32x4*)(y + (size_t)t * DD + d);
  #pragma unroll
  for (int k = 0; k < 4; k++) {
    const int es = eslot[t * 4 + k];
    const int row = offs[es >> 16] + (es & 0xFFFF);
    accv += *(const f32x4*)(outr + (size_t)row * DD + d);
  }
  *(f32x4*)(y + (size_t)t * DD + d) = accv;
}

// ---------------- launch ----------------
extern "C" void kernel_launch(void* const* d_in, const int* in_sizes, int n_in,
                              void* d_out, int out_size, void* d_ws, size_t ws_size,
                              hipStream_t stream) {
  const float* x      = (const float*)d_in[0];
  const float* gate_w = (const float*)d_in[1];
  const float* gate_b = (const float*)d_in[2];
  const float* w1     = (const float*)d_in[3];
  const float* w3     = (const float*)d_in[4];
  const float* w2     = (const float*)d_in[5];
  const float* ws1    = (const float*)d_in[6];
  const float* ws3    = (const float*)d_in[7];
  const float* ws2    = (const float*)d_in[8];
  float* y = (float*)d_out;

  char* ws = (char*)d_ws;
  // layout: counts@0, tok@1024 (128KB), wgt (128KB), eslot (32KB),
  //         bf16 area, act_r, act_s.  Total ~100 MB.
  int*   counts = (int*)ws;
  int*   tok    = (int*)(ws + 1024);
  float* wgt    = (float*)(ws + 1024 + (size_t)EE * CAP * 4);
  int*   eslot  = (int*)(ws + 1024 + (size_t)EE * CAP * 8);
  short* bf     = (short*)(ws + 1024 + (size_t)EE * CAP * 8 + (size_t)TT * 16);
  short* xb   = bf;
  short* w1b  = bf + O1;
  short* w3b  = bf + O2;
  short* w2b  = bf + O3;
  short* ws1b = bf + O4;
  short* ws3b = bf + O5;
  short* ws2b = bf + O6;
  short* act_r = bf + CVT_TOTAL;                 // [8192][704] bf16
  short* act_s = act_r + (size_t)8192 * HH;      // [2048][1408] bf16
  // outr (fp32 [8192][1024], 33.5 MB) aliases w1b/w3b (46 MB, dead after gemm1)
  float* outr = (float*)(bf + O1);

  (void)hipMemsetAsync(counts, 0, 256, stream);

  cvt_gate<<<CVT_BLOCKS + TT / 4, 256, 0, stream>>>(
      x, w1, w3, w2, ws1, ws3, ws2, bf,
      gate_w, gate_b, counts, tok, wgt, eslot);

  gemm1_merged<<<dim3(11, TT / 128, EE + 1), 256, 0, stream>>>(
      xb, w1b, w3b, ws1b, ws3b, act_r, act_s, counts, tok);

  gemm2_merged<<<dim3(DD / 128, TT / 128, EE + 1), 256, 0, stream>>>(
      act_r, act_s, w2b, ws2b, y, outr, counts, wgt);

  combine_kernel<<<TT, 256, 0, stream>>>(y, outr, eslot, counts);
}